// Round 4
// baseline (335.732 us; speedup 1.0000x reference)
//
#include <hip/hip_runtime.h>

// ---------------------------------------------------------------------------
// SpatialHead round 3: latency-focused restructure.
// - 512-thread blocks (8 waves), N-dim split across wave pairs (wave = row,nt)
// - coord conv: double-buffered LDS chunk pipeline (VGPR prefetch of fp32
//   features overlaps MFMA), coord-channel contribution precomputed as a
//   fp32 field in prep (data-independent).
// - offset conv fused into deform kernel; deform taps pipelined (gather k+1
//   prefetched during MFMA of tap k).
// MFMA 32x32x16_bf16: A[m=lane&31][k=(lane>>5)*8+j], B[n=lane&31][same k],
// D col(n)=lane&31, row(m)=(reg&3)+8*(reg>>2)+4*(lane>>5).
// LDS px stride 72 u16 (36 dw == 4 mod 32): b128 reads/stores conflict-free
// (verified R2: SQ_LDS_BANK_CONFLICT ~9e4, negligible).
// ---------------------------------------------------------------------------

typedef unsigned short u16;
typedef unsigned int u32;
typedef __attribute__((ext_vector_type(8)))  short bf16x8;
typedef __attribute__((ext_vector_type(16))) float f32x16;

#define EPSBN 1e-5f

__device__ __forceinline__ u16 f2bf(float f) {          // RNE fp32->bf16
  u32 u = __builtin_bit_cast(u32, f);
  u32 r = u + 0x7FFFu + ((u >> 16) & 1u);
  return (u16)(r >> 16);
}
__device__ __forceinline__ u32 pk2(float a, float b) {
  return (u32)f2bf(a) | ((u32)f2bf(b) << 16);
}
__device__ __forceinline__ float lo2f(u32 w) { return __builtin_bit_cast(float, w << 16); }
__device__ __forceinline__ float hi2f(u32 w) { return __builtin_bit_cast(float, w & 0xFFFF0000u); }

// ws layout (bytes)
#define O_X1   0u
#define O_X2   9437184u
#define O_X3   18874368u
#define O_PRE  28311552u
#define O_WCF  30670848u
#define O_WOF  30965760u
#define O_WDF  31002624u
#define O_WR1  31076352u
#define O_WR2  31150080u

#define N_WCF 147456
#define N_WOF 18432
#define N_W64 36864
#define N_PRE 589824
#define N_TOT (N_WCF + N_WOF + 3*N_W64 + N_PRE)

__global__ __launch_bounds__(256) void prep_kernel(
    const float* __restrict__ coord_w, const float* __restrict__ coord_b,
    const float* __restrict__ off_w, const float* __restrict__ dc_w,
    const float* __restrict__ r1_w, const float* __restrict__ r2_w,
    u16* __restrict__ wcf, u16* __restrict__ wof, u16* __restrict__ wdf,
    u16* __restrict__ wr1, u16* __restrict__ wr2, float* __restrict__ pre)
{
  int i = blockIdx.x * 256 + threadIdx.x;
  if (i >= N_TOT) return;
  int d = i;
  if (d < N_WCF) {
    int j = d & 7, lane = (d >> 3) & 63, frag = d >> 9;
    int nt = frag & 1, h = (frag >> 1) & 3, tap = (frag >> 3) % 9, cc = (frag >> 3) / 9;
    int ic = cc * 64 + h * 16 + ((lane >> 5) << 3) + j;
    int oc = nt * 32 + (lane & 31);
    wcf[d] = f2bf(coord_w[((size_t)oc * 258 + ic) * 9 + tap]);
    return;
  }
  d -= N_WCF;
  if (d < N_WOF) {
    int j = d & 7, lane = (d >> 3) & 63, frag = d >> 9;
    int h = frag & 3, tap = frag >> 2;
    int ic = h * 16 + ((lane >> 5) << 3) + j;
    int oc = lane & 31;
    wof[d] = (oc < 18) ? f2bf(off_w[((size_t)oc * 64 + ic) * 9 + tap]) : (u16)0;
    return;
  }
  d -= N_WOF;
  if (d < 3 * N_W64) {
    int seg = d / N_W64;
    int e = d - seg * N_W64;
    int j = e & 7, lane = (e >> 3) & 63, frag = e >> 9;
    int nt = frag & 1, h = (frag >> 1) & 3, tap = frag >> 3;
    int ic = h * 16 + ((lane >> 5) << 3) + j;
    int oc = nt * 32 + (lane & 31);
    const float* src = (seg == 0) ? dc_w : (seg == 1) ? r1_w : r2_w;
    u16* dst = (seg == 0) ? wdf : (seg == 1) ? wr1 : wr2;
    dst[e] = f2bf(src[((size_t)oc * 64 + ic) * 9 + tap]);
    return;
  }
  d -= 3 * N_W64;
  int oc = d & 63;
  int r = d >> 6;
  int x = r % 96, y = r / 96;
  float s = coord_b[oc];
  #pragma unroll
  for (int tap = 0; tap < 9; ++tap) {
    const int dy = tap / 3, dx = tap - dy * 3;
    const int sy = y + dy - 1, sx = x + dx - 1;
    if ((unsigned)sy < 96u && (unsigned)sx < 96u) {
      const float xx = -1.f + (2.f / 95.f) * (float)sx;
      const float yy = -1.f + (2.f / 95.f) * (float)sy;
      s += coord_w[((size_t)oc * 258 + 256) * 9 + tap] * xx
         + coord_w[((size_t)oc * 258 + 257) * 9 + tap] * yy;
    }
  }
  pre[((size_t)(y * 96 + x) << 6) + oc] = s;
}

__global__ __launch_bounds__(512, 4) void coord_conv_kernel(
    const float* __restrict__ feat, const u16* __restrict__ wcf,
    const float* __restrict__ pre,
    const float* __restrict__ g, const float* __restrict__ bb,
    const float* __restrict__ m, const float* __restrict__ v,
    u16* __restrict__ x1b)
{
  __shared__ __align__(16) u16 buf[2][204 * 72];
  const int t = threadIdx.x;
  const int wv = t >> 6, lane = t & 63;
  const int l31 = lane & 31, l5 = lane >> 5;
  const int row = wv >> 1, nt = wv & 1;
  const int x0 = blockIdx.x * 32, y0 = blockIdx.y * 4, b = blockIdx.z;

  int rpx[4], rgg[4]; size_t rgo[4]; bool rok[4], ract[4];
  #pragma unroll
  for (int it = 0; it < 4; ++it) {
    int r = t + it * 512;
    ract[it] = (r < 1632);
    int px = r >> 3; if (px > 203) px = 203;
    rgg[it] = r & 7;
    rpx[it] = px;
    int ly = px / 34, lx = px - ly * 34;
    int gy = y0 + ly - 1, gx = x0 + lx - 1;
    rok[it] = ract[it] && ((unsigned)gy < 96u) && ((unsigned)gx < 96u);
    rgo[it] = ((size_t)((b * 96 + gy) * 96 + gx)) * 256 + rgg[it] * 8;
  }

  float4 ra[4][2];
  #pragma unroll
  for (int it = 0; it < 4; ++it) {
    ra[it][0] = make_float4(0.f, 0.f, 0.f, 0.f);
    ra[it][1] = make_float4(0.f, 0.f, 0.f, 0.f);
    if (rok[it]) {
      const float* p = feat + rgo[it];
      ra[it][0] = *(const float4*)p;
      ra[it][1] = *(const float4*)(p + 4);
    }
  }
  #pragma unroll
  for (int it = 0; it < 4; ++it) if (ract[it]) {
    uint4 o = {pk2(ra[it][0].x, ra[it][0].y), pk2(ra[it][0].z, ra[it][0].w),
               pk2(ra[it][1].x, ra[it][1].y), pk2(ra[it][1].z, ra[it][1].w)};
    *(uint4*)(&buf[0][rpx[it] * 72 + rgg[it] * 8]) = o;
  }
  __syncthreads();

  f32x16 acc = {};
  for (int cc = 0; cc < 4; ++cc) {
    const int cur = cc & 1;
    if (cc < 3) {
      #pragma unroll
      for (int it = 0; it < 4; ++it) {
        ra[it][0] = make_float4(0.f, 0.f, 0.f, 0.f);
        ra[it][1] = make_float4(0.f, 0.f, 0.f, 0.f);
        if (rok[it]) {
          const float* p = feat + rgo[it] + (size_t)(cc + 1) * 64;
          ra[it][0] = *(const float4*)p;
          ra[it][1] = *(const float4*)(p + 4);
        }
      }
    }
    #pragma unroll
    for (int tap = 0; tap < 9; ++tap) {
      const int dy = tap / 3, dx = tap - dy * 3;
      #pragma unroll
      for (int h = 0; h < 4; ++h) {
        const bf16x8 afr = *(const bf16x8*)(
            &buf[cur][((row + dy) * 34 + l31 + dx) * 72 + h * 16 + l5 * 8]);
        const bf16x8 bfr = *(const bf16x8*)(
            wcf + ((size_t)(((cc * 9 + tap) * 4 + h) * 2 + nt)) * 512 + lane * 8);
        acc = __builtin_amdgcn_mfma_f32_32x32x16_bf16(afr, bfr, acc, 0, 0, 0);
      }
    }
    if (cc < 3) {
      #pragma unroll
      for (int it = 0; it < 4; ++it) if (ract[it]) {
        uint4 o = {pk2(ra[it][0].x, ra[it][0].y), pk2(ra[it][0].z, ra[it][0].w),
                   pk2(ra[it][1].x, ra[it][1].y), pk2(ra[it][1].z, ra[it][1].w)};
        *(uint4*)(&buf[1 - cur][rpx[it] * 72 + rgg[it] * 8]) = o;
      }
    }
    __syncthreads();
  }

  const int oc = nt * 32 + l31;
  const float inv = g[oc] * rsqrtf(v[oc] + EPSBN);
  const float sh = bb[oc] - m[oc] * inv;
  const int y = y0 + row;
  #pragma unroll
  for (int r = 0; r < 16; ++r) {
    const int xr = (r & 3) + 8 * (r >> 2) + 4 * l5;
    const int x = x0 + xr;
    const float pv = pre[((size_t)(y * 96 + x) << 6) + oc];
    const float val = fmaxf(fmaf(acc[r] + pv, inv, sh), 0.f);
    x1b[(((size_t)((b * 96 + y) * 96 + x)) << 6) + oc] = f2bf(val);
  }
}

template<int EPI>
__global__ __launch_bounds__(512, 4) void conv64_kernel(
    const u16* __restrict__ xin, const u16* __restrict__ wf,
    const float* __restrict__ g, const float* __restrict__ bb,
    const float* __restrict__ m, const float* __restrict__ v,
    const float* __restrict__ ow, const float* __restrict__ ob,
    void* __restrict__ outp)
{
  __shared__ __align__(16) u16 tile[204 * 72];
  __shared__ float red[128];
  const int t = threadIdx.x;
  const int wv = t >> 6, lane = t & 63;
  const int l31 = lane & 31, l5 = lane >> 5;
  const int row = wv >> 1, nt = wv & 1;
  const int x0 = blockIdx.x * 32, y0 = blockIdx.y * 4, b = blockIdx.z;

  if constexpr (EPI == 2) { if (t < 128) red[t] = 0.f; }

  #pragma unroll
  for (int it = 0; it < 4; ++it) {
    int r = t + it * 512;
    if (r < 1632) {
      int px = r >> 3, gg = r & 7;
      int ly = px / 34, lx = px - ly * 34;
      int gy = y0 + ly - 1, gx = x0 + lx - 1;
      uint4 o = {0u, 0u, 0u, 0u};
      if ((unsigned)gy < 96u && (unsigned)gx < 96u)
        o = *(const uint4*)(xin + (((size_t)((b * 96 + gy) * 96 + gx)) << 6)
                            + gg * 8);
      *(uint4*)(&tile[px * 72 + gg * 8]) = o;
    }
  }
  __syncthreads();

  f32x16 acc = {};
  #pragma unroll
  for (int tap = 0; tap < 9; ++tap) {
    const int dy = tap / 3, dx = tap - dy * 3;
    #pragma unroll
    for (int h = 0; h < 4; ++h) {
      const bf16x8 afr = *(const bf16x8*)(
          &tile[((row + dy) * 34 + l31 + dx) * 72 + h * 16 + l5 * 8]);
      const bf16x8 bfr = *(const bf16x8*)(
          wf + ((size_t)((tap * 4 + h) * 2 + nt)) * 512 + lane * 8);
      acc = __builtin_amdgcn_mfma_f32_32x32x16_bf16(afr, bfr, acc, 0, 0, 0);
    }
  }

  const int oc = nt * 32 + l31;
  const float inv = g[oc] * rsqrtf(v[oc] + EPSBN);
  const float sh = bb[oc] - m[oc] * inv;
  const int y = y0 + row;

  if constexpr (EPI == 0) {
    u16* xo = (u16*)outp;
    #pragma unroll
    for (int r = 0; r < 16; ++r) {
      const int xr = (r & 3) + 8 * (r >> 2) + 4 * l5;
      const float val = fmaxf(fmaf(acc[r], inv, sh), 0.f);
      xo[(((size_t)((b * 96 + y) * 96 + x0 + xr)) << 6) + oc] = f2bf(val);
    }
  } else {
    const float wo = ow[oc];
    float pr[16];
    #pragma unroll
    for (int r = 0; r < 16; ++r)
      pr[r] = fmaxf(fmaf(acc[r], inv, sh), 0.f) * wo;
    #pragma unroll
    for (int mask = 1; mask <= 16; mask <<= 1)
      #pragma unroll
      for (int r = 0; r < 16; ++r)
        pr[r] += __shfl_xor(pr[r], mask);
    if (l31 == 0) {
      #pragma unroll
      for (int r = 0; r < 16; ++r) {
        const int xr = (r & 3) + 8 * (r >> 2) + 4 * l5;
        atomicAdd(&red[row * 32 + xr], pr[r]);
      }
    }
    __syncthreads();
    if (t < 128) {
      float* fo = (float*)outp;
      const int yy = y0 + (t >> 5), xx = x0 + (t & 31);
      const float val = red[t] + ob[0];
      fo[(size_t)(b * 96 + yy) * 96 + xx] = 1.f / (1.f + expf(-val));
    }
  }
}

__global__ __launch_bounds__(512, 4) void offdeform_kernel(
    const u16* __restrict__ x1b, const u16* __restrict__ wof,
    const u16* __restrict__ wdf, const float* __restrict__ off_b,
    const float* __restrict__ g, const float* __restrict__ bb,
    const float* __restrict__ m, const float* __restrict__ v,
    u16* __restrict__ x2b)
{
  __shared__ __align__(16) char arena[9216 + 36864];
  float* offs = (float*)arena;
  u16* halo = (u16*)(arena + 9216);
  u16* sb0 = (u16*)(arena + 9216);
  u16* sb1 = (u16*)(arena + 9216 + 18432);
  const int t = threadIdx.x;
  const int wv = t >> 6, lane = t & 63;
  const int l31 = lane & 31, l5 = lane >> 5;
  const int mtile = wv >> 1, nt = wv & 1;
  const int x0 = blockIdx.x * 16, y0 = blockIdx.y * 8, b = blockIdx.z;

  #pragma unroll
  for (int it = 0; it < 3; ++it) {
    int r = t + it * 512;
    if (r < 1440) {
      int px = r >> 3, gg = r & 7;
      int hy = px / 18, hx = px - hy * 18;
      int gy = y0 + hy - 1, gx = x0 + hx - 1;
      uint4 o = {0u, 0u, 0u, 0u};
      if ((unsigned)gy < 96u && (unsigned)gx < 96u)
        o = *(const uint4*)(x1b + (((size_t)((b * 96 + gy) * 96 + gx)) << 6)
                            + gg * 8);
      *(uint4*)(&halo[px * 72 + gg * 8]) = o;
    }
  }
  __syncthreads();

  if (wv < 4) {
    const int om = wv * 32 + l31;
    const int oy_ = om >> 4, ox_ = om & 15;
    f32x16 oacc = {};
    #pragma unroll
    for (int tap = 0; tap < 9; ++tap) {
      const int dy = tap / 3, dx = tap - dy * 3;
      #pragma unroll
      for (int h = 0; h < 4; ++h) {
        const bf16x8 afr = *(const bf16x8*)(
            &halo[((oy_ + dy) * 18 + ox_ + dx) * 72 + h * 16 + l5 * 8]);
        const bf16x8 bfr = *(const bf16x8*)(
            wof + ((size_t)(tap * 4 + h)) * 512 + lane * 8);
        oacc = __builtin_amdgcn_mfma_f32_32x32x16_bf16(afr, bfr, oacc, 0, 0, 0);
      }
    }
    if (l31 < 18) {
      const float bs = off_b[l31];
      #pragma unroll
      for (int r = 0; r < 16; ++r) {
        const int p = wv * 32 + (r & 3) + 8 * (r >> 2) + 4 * l5;
        offs[p * 18 + l31] = oacc[r] + bs;
      }
    }
  }
  __syncthreads();

  const int gg = t & 7, p0 = t >> 3;
  f32x16 acc = {};
  uint4 cv[2][4];
  float cw[2][4];

  auto gather = [&](int k) {
    const int kdy = k / 3, kdx = k - kdy * 3;
    #pragma unroll
    for (int rr = 0; rr < 2; ++rr) {
      const int p = p0 + rr * 64;
      const float oy = offs[p * 18 + 2 * k];
      const float ox = offs[p * 18 + 2 * k + 1];
      const float py = (float)(y0 + (p >> 4) + kdy - 1) + oy;
      const float pxf = (float)(x0 + (p & 15) + kdx - 1) + ox;
      const float yf = floorf(py), xf = floorf(pxf);
      const float fy = py - yf, fx = pxf - xf;
      const int yi = (int)yf, xi = (int)xf;
      #pragma unroll
      for (int cor = 0; cor < 4; ++cor) {
        const int cy = yi + (cor >> 1), cx = xi + (cor & 1);
        const bool okc = ((unsigned)cy < 96u) && ((unsigned)cx < 96u);
        const float wy = (cor & 2) ? fy : 1.f - fy;
        const float wx = (cor & 1) ? fx : 1.f - fx;
        cw[rr][cor] = okc ? wy * wx : 0.f;
        uint4 z = {0u, 0u, 0u, 0u};
        cv[rr][cor] = okc ? *(const uint4*)(x1b +
            (((size_t)((b * 96 + cy) * 96 + cx)) << 6) + gg * 8) : z;
      }
    }
  };
  auto blend_store = [&](u16* dst) {
    #pragma unroll
    for (int rr = 0; rr < 2; ++rr) {
      const int p = p0 + rr * 64;
      float o8[8];
      #pragma unroll
      for (int u = 0; u < 8; ++u) o8[u] = 0.f;
      #pragma unroll
      for (int cor = 0; cor < 4; ++cor) {
        const float wgt = cw[rr][cor];
        const u32 uu[4] = {cv[rr][cor].x, cv[rr][cor].y,
                           cv[rr][cor].z, cv[rr][cor].w};
        #pragma unroll
        for (int u = 0; u < 4; ++u) {
          o8[2 * u]     = fmaf(wgt, lo2f(uu[u]), o8[2 * u]);
          o8[2 * u + 1] = fmaf(wgt, hi2f(uu[u]), o8[2 * u + 1]);
        }
      }
      uint4 w_;
      w_.x = pk2(o8[0], o8[1]); w_.y = pk2(o8[2], o8[3]);
      w_.z = pk2(o8[4], o8[5]); w_.w = pk2(o8[6], o8[7]);
      *(uint4*)(&dst[p * 72 + gg * 8]) = w_;
    }
  };

  gather(0);
  blend_store(sb0);
  __syncthreads();

  for (int k = 0; k < 9; ++k) {
    u16* curb = (k & 1) ? sb1 : sb0;
    u16* nxtb = (k & 1) ? sb0 : sb1;
    if (k < 8) gather(k + 1);
    #pragma unroll
    for (int h = 0; h < 4; ++h) {
      const bf16x8 afr = *(const bf16x8*)(
          &curb[(mtile * 32 + l31) * 72 + h * 16 + l5 * 8]);
      const bf16x8 bfr = *(const bf16x8*)(
          wdf + ((size_t)((k * 4 + h) * 2 + nt)) * 512 + lane * 8);
      acc = __builtin_amdgcn_mfma_f32_32x32x16_bf16(afr, bfr, acc, 0, 0, 0);
    }
    if (k < 8) blend_store(nxtb);
    __syncthreads();
  }

  const int oc = nt * 32 + l31;
  const float inv = g[oc] * rsqrtf(v[oc] + EPSBN);
  const float sh = bb[oc] - m[oc] * inv;
  #pragma unroll
  for (int r = 0; r < 16; ++r) {
    const int p = mtile * 32 + (r & 3) + 8 * (r >> 2) + 4 * l5;
    const int y = y0 + (p >> 4), x = x0 + (p & 15);
    const float val = fmaxf(fmaf(acc[r], inv, sh), 0.f);
    x2b[(((size_t)((b * 96 + y) * 96 + x)) << 6) + oc] = f2bf(val);
  }
}

extern "C" void kernel_launch(void* const* d_in, const int* in_sizes, int n_in,
                              void* d_out, int out_size, void* d_ws,
                              size_t ws_size, hipStream_t stream)
{
  (void)in_sizes; (void)n_in; (void)out_size; (void)ws_size;
  const float* features = (const float*)d_in[0];
  const float* coord_w  = (const float*)d_in[1];
  const float* coord_b  = (const float*)d_in[2];
  const float* bn1g = (const float*)d_in[3];
  const float* bn1b = (const float*)d_in[4];
  const float* bn1m = (const float*)d_in[5];
  const float* bn1v = (const float*)d_in[6];
  const float* off_w = (const float*)d_in[7];
  const float* off_b = (const float*)d_in[8];
  const float* dc_w  = (const float*)d_in[9];
  const float* bn2g = (const float*)d_in[10];
  const float* bn2b = (const float*)d_in[11];
  const float* bn2m = (const float*)d_in[12];
  const float* bn2v = (const float*)d_in[13];
  const float* r1_w = (const float*)d_in[14];
  const float* bn3g = (const float*)d_in[15];
  const float* bn3b = (const float*)d_in[16];
  const float* bn3m = (const float*)d_in[17];
  const float* bn3v = (const float*)d_in[18];
  const float* r2_w = (const float*)d_in[19];
  const float* bn4g = (const float*)d_in[20];
  const float* bn4b = (const float*)d_in[21];
  const float* bn4m = (const float*)d_in[22];
  const float* bn4v = (const float*)d_in[23];
  const float* out_w = (const float*)d_in[24];
  const float* out_b = (const float*)d_in[25];

  char* W = (char*)d_ws;
  u16*   x1b = (u16*)(W + O_X1);
  u16*   x2b = (u16*)(W + O_X2);
  u16*   x3b = (u16*)(W + O_X3);
  float* pre = (float*)(W + O_PRE);
  u16*   wcf = (u16*)(W + O_WCF);
  u16*   wof = (u16*)(W + O_WOF);
  u16*   wdf = (u16*)(W + O_WDF);
  u16*   wr1 = (u16*)(W + O_WR1);
  u16*   wr2 = (u16*)(W + O_WR2);

  prep_kernel<<<(N_TOT + 255) / 256, 256, 0, stream>>>(
      coord_w, coord_b, off_w, dc_w, r1_w, r2_w, wcf, wof, wdf, wr1, wr2, pre);

  dim3 grid(3, 24, 8);   // 32x4 tiles
  dim3 gridD(6, 12, 8);  // 16x8 tiles (deform)

  coord_conv_kernel<<<grid, 512, 0, stream>>>(
      features, wcf, pre, bn1g, bn1b, bn1m, bn1v, x1b);
  offdeform_kernel<<<gridD, 512, 0, stream>>>(
      x1b, wof, wdf, off_b, bn2g, bn2b, bn2m, bn2v, x2b);
  conv64_kernel<0><<<grid, 512, 0, stream>>>(
      x2b, wr1, bn3g, bn3b, bn3m, bn3v, nullptr, nullptr, (void*)x3b);
  conv64_kernel<2><<<grid, 512, 0, stream>>>(
      x3b, wr2, bn4g, bn4b, bn4m, bn4v, out_w, out_b, d_out);
}

// Round 7
// 298.489 us; speedup vs baseline: 1.1248x; 1.1248x over previous
//
#include <hip/hip_runtime.h>

// ---------------------------------------------------------------------------
// SpatialHead round 6 (= round 5 + x0b sizing fix: N_X0G was HALF the
// feature granule count, leaving half of x0b as 0xAA poison).
// - prep: weights -> MFMA frags, features -> bf16 NHWC, coord field -> fp32.
// - coord conv: double-buffered bf16 chunk pipeline (4 chunks of 64 ch).
// - offset conv: conv64 EPI=1 (fp32 [b][96][96][18] out), wof padded
//   [tap][h][nt2] (nt=1 zero).
// - deform: register-direct gather, NO barriers in tap loop.
// MFMA 32x32x16_bf16: A[m=lane&31][k=(lane>>5)*8+j], B[n=lane&31][same],
// D col(n)=lane&31, row m=(reg&3)+8*(reg>>2)+4*(lane>>5).
// LDS px stride 72 u16 -> conflict-free b128 (verified R2: ~9e4 conflicts).
// ws aliasing: x0b dead after coord conv; x2b/x3b live inside its region.
// ---------------------------------------------------------------------------

typedef unsigned short u16;
typedef unsigned int u32;
typedef __attribute__((ext_vector_type(8)))  short bf16x8;
typedef __attribute__((ext_vector_type(16))) float f32x16;

#define EPSBN 1e-5f

__device__ __forceinline__ u16 f2bf(float f) {          // RNE fp32->bf16
  u32 u = __builtin_bit_cast(u32, f);
  u32 r = u + 0x7FFFu + ((u >> 16) & 1u);
  return (u16)(r >> 16);
}
__device__ __forceinline__ u32 pk2(float a, float b) {
  return (u32)f2bf(a) | ((u32)f2bf(b) << 16);
}
__device__ __forceinline__ float lo2f(u32 w) { return __builtin_bit_cast(float, w << 16); }
__device__ __forceinline__ float hi2f(u32 w) { return __builtin_bit_cast(float, w & 0xFFFF0000u); }

// ws layout (bytes)
#define O_X1   0u           // bf16 8*96*96*64                =  9,437,184 B
#define O_X0B  9437184u     // bf16 8*96*96*256               = 37,748,736 B
#define O_X2   9437184u     //   alias in x0b (x0b dead after coord conv)
#define O_X3   18874368u    //   alias in x0b
#define O_OFF  47185920u    // fp32 8*96*96*18                =  5,308,416 B
#define O_PRE  52494336u    // fp32 96*96*64                  =  2,359,296 B
#define O_WCF  54853632u    // u16 147456                     =    294,912 B
#define O_WOF  55148544u    // u16 36864                      =     73,728 B
#define O_WDF  55222272u
#define O_WR1  55296000u
#define O_WR2  55369728u    // end 55,443,456

#define N_X0G 2359296       // 8-elem granules of features (18,874,368 / 8)
#define N_WCF 147456
#define N_WOF 36864         // [tap9][h4][nt2]*512, nt=1 zero
#define N_W64 36864
#define N_PRE 589824
#define N_TOT (N_X0G + N_WCF + N_WOF + 3*N_W64 + N_PRE)

__global__ __launch_bounds__(256) void prep_kernel(
    const float* __restrict__ feat,
    const float* __restrict__ coord_w, const float* __restrict__ coord_b,
    const float* __restrict__ off_w, const float* __restrict__ dc_w,
    const float* __restrict__ r1_w, const float* __restrict__ r2_w,
    u16* __restrict__ x0b,
    u16* __restrict__ wcf, u16* __restrict__ wof, u16* __restrict__ wdf,
    u16* __restrict__ wr1, u16* __restrict__ wr2, float* __restrict__ pre)
{
  for (int i = blockIdx.x * 256 + threadIdx.x; i < N_TOT;
       i += gridDim.x * 256) {
    int d = i;
    if (d < N_X0G) {  // features fp32 -> bf16, 8 ch per item
      const float* p = feat + (size_t)d * 8;
      const float4 f0 = *(const float4*)p;
      const float4 f1 = *(const float4*)(p + 4);
      uint4 o = {pk2(f0.x, f0.y), pk2(f0.z, f0.w),
                 pk2(f1.x, f1.y), pk2(f1.z, f1.w)};
      ((uint4*)x0b)[d] = o;
      continue;
    }
    d -= N_X0G;
    if (d < N_WCF) {
      int j = d & 7, lane = (d >> 3) & 63, frag = d >> 9;
      int nt = frag & 1, h = (frag >> 1) & 3, tap = (frag >> 3) % 9, cc = (frag >> 3) / 9;
      int ic = cc * 64 + h * 16 + ((lane >> 5) << 3) + j;
      int oc = nt * 32 + (lane & 31);
      wcf[d] = f2bf(coord_w[((size_t)oc * 258 + ic) * 9 + tap]);
      continue;
    }
    d -= N_WCF;
    if (d < N_WOF) {  // [tap][h][nt2]: nt=0 -> oc 0..31 (18 real), nt=1 -> 0
      int j = d & 7, lane = (d >> 3) & 63, frag = d >> 9;
      int nt = frag & 1, h = (frag >> 1) & 3, tap = frag >> 3;
      int ic = h * 16 + ((lane >> 5) << 3) + j;
      int oc = lane & 31;
      wof[d] = (nt == 0 && oc < 18)
                   ? f2bf(off_w[((size_t)oc * 64 + ic) * 9 + tap]) : (u16)0;
      continue;
    }
    d -= N_WOF;
    if (d < 3 * N_W64) {
      int seg = d / N_W64;
      int e = d - seg * N_W64;
      int j = e & 7, lane = (e >> 3) & 63, frag = e >> 9;
      int nt = frag & 1, h = (frag >> 1) & 3, tap = frag >> 3;
      int ic = h * 16 + ((lane >> 5) << 3) + j;
      int oc = nt * 32 + (lane & 31);
      const float* src = (seg == 0) ? dc_w : (seg == 1) ? r1_w : r2_w;
      u16* dst = (seg == 0) ? wdf : (seg == 1) ? wr1 : wr2;
      dst[e] = f2bf(src[((size_t)oc * 64 + ic) * 9 + tap]);
      continue;
    }
    d -= 3 * N_W64;
    int oc = d & 63;
    int r = d >> 6;
    int x = r % 96, y = r / 96;
    float s = coord_b[oc];
    #pragma unroll
    for (int tap = 0; tap < 9; ++tap) {
      const int dy = tap / 3, dx = tap - dy * 3;
      const int sy = y + dy - 1, sx = x + dx - 1;
      if ((unsigned)sy < 96u && (unsigned)sx < 96u) {
        const float xx = -1.f + (2.f / 95.f) * (float)sx;
        const float yy = -1.f + (2.f / 95.f) * (float)sy;
        s += coord_w[((size_t)oc * 258 + 256) * 9 + tap] * xx
           + coord_w[((size_t)oc * 258 + 257) * 9 + tap] * yy;
      }
    }
    pre[((size_t)(y * 96 + x) << 6) + oc] = s;
  }
}

// ---------------------------------------------------------------------------
// Coord conv 256ch -> 64 + precomputed coord field + BN1 + ReLU -> x1b.
// 512 thr, 8 waves = (row, nt). Double-buffered bf16 chunks of 64 ch.
// ---------------------------------------------------------------------------
__global__ __launch_bounds__(512, 4) void coord_conv_kernel(
    const u16* __restrict__ x0b, const u16* __restrict__ wcf,
    const float* __restrict__ pre,
    const float* __restrict__ g, const float* __restrict__ bb,
    const float* __restrict__ m, const float* __restrict__ v,
    u16* __restrict__ x1b)
{
  __shared__ __align__(16) u16 buf[2][204 * 72];
  const int t = threadIdx.x;
  const int wv = t >> 6, lane = t & 63;
  const int l31 = lane & 31, l5 = lane >> 5;
  const int row = wv >> 1, nt = wv & 1;
  const int x0 = blockIdx.x * 32, y0 = blockIdx.y * 4, b = blockIdx.z;

  int rpx[4], rgg[4]; size_t rgo[4]; bool rok[4], ract[4];
  #pragma unroll
  for (int it = 0; it < 4; ++it) {
    int r = t + it * 512;
    ract[it] = (r < 1632);
    int px = r >> 3; if (px > 203) px = 203;
    rgg[it] = r & 7;
    rpx[it] = px;
    int ly = px / 34, lx = px - ly * 34;
    int gy = y0 + ly - 1, gx = x0 + lx - 1;
    rok[it] = ract[it] && ((unsigned)gy < 96u) && ((unsigned)gx < 96u);
    rgo[it] = (((size_t)((b * 96 + gy) * 96 + gx)) << 8) + rgg[it] * 8;
  }

  uint4 ra[4];
  #pragma unroll
  for (int it = 0; it < 4; ++it) {
    ra[it] = make_uint4(0u, 0u, 0u, 0u);
    if (rok[it]) ra[it] = *(const uint4*)(x0b + rgo[it]);
  }
  #pragma unroll
  for (int it = 0; it < 4; ++it) if (ract[it])
    *(uint4*)(&buf[0][rpx[it] * 72 + rgg[it] * 8]) = ra[it];
  __syncthreads();

  f32x16 acc = {};
  for (int cc = 0; cc < 4; ++cc) {
    const int cur = cc & 1;
    if (cc < 3) {  // prefetch next chunk while MFMA runs
      #pragma unroll
      for (int it = 0; it < 4; ++it) {
        ra[it] = make_uint4(0u, 0u, 0u, 0u);
        if (rok[it]) ra[it] = *(const uint4*)(x0b + rgo[it] + (cc + 1) * 64);
      }
    }
    #pragma unroll
    for (int tap = 0; tap < 9; ++tap) {
      const int dy = tap / 3, dx = tap - dy * 3;
      #pragma unroll
      for (int h = 0; h < 4; ++h) {
        const bf16x8 afr = *(const bf16x8*)(
            &buf[cur][((row + dy) * 34 + l31 + dx) * 72 + h * 16 + l5 * 8]);
        const bf16x8 bfr = *(const bf16x8*)(
            wcf + ((size_t)(((cc * 9 + tap) * 4 + h) * 2 + nt)) * 512 + lane * 8);
        acc = __builtin_amdgcn_mfma_f32_32x32x16_bf16(afr, bfr, acc, 0, 0, 0);
      }
    }
    if (cc < 3) {
      #pragma unroll
      for (int it = 0; it < 4; ++it) if (ract[it])
        *(uint4*)(&buf[1 - cur][rpx[it] * 72 + rgg[it] * 8]) = ra[it];
    }
    __syncthreads();
  }

  const int oc = nt * 32 + l31;
  const float inv = g[oc] * rsqrtf(v[oc] + EPSBN);
  const float sh = bb[oc] - m[oc] * inv;
  const int y = y0 + row;
  #pragma unroll
  for (int r = 0; r < 16; ++r) {
    const int xr = (r & 3) + 8 * (r >> 2) + 4 * l5;
    const int x = x0 + xr;
    const float pv = pre[((size_t)(y * 96 + x) << 6) + oc];
    const float val = fmaxf(fmaf(acc[r] + pv, inv, sh), 0.f);
    x1b[(((size_t)((b * 96 + y) * 96 + x)) << 6) + oc] = f2bf(val);
  }
}

// ---------------------------------------------------------------------------
// 64->64 3x3 conv, 512 thr, 8 waves (row, nt).
// EPI 0: BN+ReLU -> bf16. EPI 1: +bias -> fp32 [18] (offset conv; bias=ow).
// EPI 2: BN+ReLU + 1x1 + sigmoid -> fp32 (B,96,96).
// ---------------------------------------------------------------------------
template<int EPI>
__global__ __launch_bounds__(512, 4) void conv64_kernel(
    const u16* __restrict__ xin, const u16* __restrict__ wf,
    const float* __restrict__ g, const float* __restrict__ bb,
    const float* __restrict__ m, const float* __restrict__ v,
    const float* __restrict__ ow, const float* __restrict__ ob,
    void* __restrict__ outp)
{
  __shared__ __align__(16) u16 tile[204 * 72];
  __shared__ float red[128];
  const int t = threadIdx.x;
  const int wv = t >> 6, lane = t & 63;
  const int l31 = lane & 31, l5 = lane >> 5;
  const int row = wv >> 1, nt = wv & 1;
  const int x0 = blockIdx.x * 32, y0 = blockIdx.y * 4, b = blockIdx.z;

  if constexpr (EPI == 2) { if (t < 128) red[t] = 0.f; }

  #pragma unroll
  for (int it = 0; it < 4; ++it) {
    int r = t + it * 512;
    if (r < 1632) {
      int px = r >> 3, gg = r & 7;
      int ly = px / 34, lx = px - ly * 34;
      int gy = y0 + ly - 1, gx = x0 + lx - 1;
      uint4 o = {0u, 0u, 0u, 0u};
      if ((unsigned)gy < 96u && (unsigned)gx < 96u)
        o = *(const uint4*)(xin + (((size_t)((b * 96 + gy) * 96 + gx)) << 6)
                            + gg * 8);
      *(uint4*)(&tile[px * 72 + gg * 8]) = o;
    }
  }
  __syncthreads();

  f32x16 acc = {};
  #pragma unroll
  for (int tap = 0; tap < 9; ++tap) {
    const int dy = tap / 3, dx = tap - dy * 3;
    #pragma unroll
    for (int h = 0; h < 4; ++h) {
      const bf16x8 afr = *(const bf16x8*)(
          &tile[((row + dy) * 34 + l31 + dx) * 72 + h * 16 + l5 * 8]);
      const bf16x8 bfr = *(const bf16x8*)(
          wf + ((size_t)((tap * 4 + h) * 2 + nt)) * 512 + lane * 8);
      acc = __builtin_amdgcn_mfma_f32_32x32x16_bf16(afr, bfr, acc, 0, 0, 0);
    }
  }

  const int y = y0 + row;
  if constexpr (EPI == 1) {
    if (nt == 0 && l31 < 18) {
      float* fo = (float*)outp;
      const float bs = ow[l31];
      #pragma unroll
      for (int r = 0; r < 16; ++r) {
        const int xr = (r & 3) + 8 * (r >> 2) + 4 * l5;
        fo[((size_t)((b * 96 + y) * 96 + x0 + xr)) * 18 + l31] = acc[r] + bs;
      }
    }
    return;
  }

  const int oc = nt * 32 + l31;
  const float inv = g[oc] * rsqrtf(v[oc] + EPSBN);
  const float sh = bb[oc] - m[oc] * inv;

  if constexpr (EPI == 0) {
    u16* xo = (u16*)outp;
    #pragma unroll
    for (int r = 0; r < 16; ++r) {
      const int xr = (r & 3) + 8 * (r >> 2) + 4 * l5;
      const float val = fmaxf(fmaf(acc[r], inv, sh), 0.f);
      xo[(((size_t)((b * 96 + y) * 96 + x0 + xr)) << 6) + oc] = f2bf(val);
    }
  } else if constexpr (EPI == 2) {
    const float wo = ow[oc];
    float pr[16];
    #pragma unroll
    for (int r = 0; r < 16; ++r)
      pr[r] = fmaxf(fmaf(acc[r], inv, sh), 0.f) * wo;
    #pragma unroll
    for (int mask = 1; mask <= 16; mask <<= 1)
      #pragma unroll
      for (int r = 0; r < 16; ++r)
        pr[r] += __shfl_xor(pr[r], mask);
    if (l31 == 0) {
      #pragma unroll
      for (int r = 0; r < 16; ++r) {
        const int xr = (r & 3) + 8 * (r >> 2) + 4 * l5;
        atomicAdd(&red[row * 32 + xr], pr[r]);
      }
    }
    __syncthreads();
    if (t < 128) {
      float* fo = (float*)outp;
      const int yy = y0 + (t >> 5), xx = x0 + (t & 31);
      const float val = red[t] + ob[0];
      fo[(size_t)(b * 96 + yy) * 96 + xx] = 1.f / (1.f + expf(-val));
    }
  }
}

// ---------------------------------------------------------------------------
// Deformable conv, register-direct. 256 thr = 4 waves; wave wv owns M-tile
// of 32 px (p = wv*32 + l31), computes both N-tiles. NO barriers in tap loop.
// Per (tap,h): each lane gathers its pixel's 8-ch group at 4 clamped corners
// (weight zeroed when invalid), blends fp32, packs bf16 -> A-frag -> 2 MFMAs.
// ---------------------------------------------------------------------------
__global__ __launch_bounds__(256, 4) void deform_kernel(
    const u16* __restrict__ x1b, const float* __restrict__ off,
    const u16* __restrict__ wdf,
    const float* __restrict__ g, const float* __restrict__ bb,
    const float* __restrict__ m, const float* __restrict__ v,
    u16* __restrict__ x2b)
{
  __shared__ float offs[128 * 18];
  const int t = threadIdx.x;
  const int wv = t >> 6, lane = t & 63;
  const int l31 = lane & 31, l5 = lane >> 5;
  const int x0 = blockIdx.x * 16, y0 = blockIdx.y * 8, b = blockIdx.z;

  for (int i = t; i < 2304; i += 256) {
    const int p = i / 18, c = i - p * 18;
    const int gy = y0 + (p >> 4), gx = x0 + (p & 15);
    offs[i] = off[((size_t)((b * 96 + gy) * 96 + gx)) * 18 + c];
  }
  __syncthreads();

  const int pa = wv * 32 + l31;              // this lane's A-pixel
  const int pay = y0 + (pa >> 4), pax = x0 + (pa & 15);

  f32x16 acc0 = {}, acc1 = {};

  for (int k = 0; k < 9; ++k) {
    const int kdy = k / 3, kdx = k - kdy * 3;
    const float oy = offs[pa * 18 + 2 * k];
    const float ox = offs[pa * 18 + 2 * k + 1];
    const float py = (float)(pay + kdy - 1) + oy;
    const float px = (float)(pax + kdx - 1) + ox;
    const float yf = floorf(py), xf = floorf(px);
    const float fy = py - yf, fx = px - xf;
    const int yi = (int)yf, xi = (int)xf;

    const u16* base[4];
    float cw[4];
    #pragma unroll
    for (int cor = 0; cor < 4; ++cor) {
      const int cy = yi + (cor >> 1), cx = xi + (cor & 1);
      const bool okc = ((unsigned)cy < 96u) && ((unsigned)cx < 96u);
      const float wy = (cor & 2) ? fy : 1.f - fy;
      const float wx = (cor & 1) ? fx : 1.f - fx;
      cw[cor] = okc ? wy * wx : 0.f;
      const int cyc = cy < 0 ? 0 : (cy > 95 ? 95 : cy);
      const int cxc = cx < 0 ? 0 : (cx > 95 ? 95 : cx);
      base[cor] = x1b + (((size_t)((b * 96 + cyc) * 96 + cxc)) << 6);
    }

    #pragma unroll
    for (int h = 0; h < 4; ++h) {
      const int chg = h * 16 + l5 * 8;
      uint4 cv[4];
      #pragma unroll
      for (int cor = 0; cor < 4; ++cor)
        cv[cor] = *(const uint4*)(base[cor] + chg);
      float o8[8];
      #pragma unroll
      for (int u = 0; u < 8; ++u) o8[u] = 0.f;
      #pragma unroll
      for (int cor = 0; cor < 4; ++cor) {
        const float wgt = cw[cor];
        const u32 uu[4] = {cv[cor].x, cv[cor].y, cv[cor].z, cv[cor].w};
        #pragma unroll
        for (int u = 0; u < 4; ++u) {
          o8[2 * u]     = fmaf(wgt, lo2f(uu[u]), o8[2 * u]);
          o8[2 * u + 1] = fmaf(wgt, hi2f(uu[u]), o8[2 * u + 1]);
        }
      }
      u32 pkd[4];
      #pragma unroll
      for (int u = 0; u < 4; ++u) pkd[u] = pk2(o8[2 * u], o8[2 * u + 1]);
      bf16x8 afr;
      #pragma unroll
      for (int u = 0; u < 4; ++u) {
        afr[2 * u]     = (short)(pkd[u] & 0xFFFFu);
        afr[2 * u + 1] = (short)(pkd[u] >> 16);
      }
      const bf16x8 bf0 = *(const bf16x8*)(
          wdf + ((size_t)((k * 4 + h) * 2 + 0)) * 512 + lane * 8);
      const bf16x8 bf1 = *(const bf16x8*)(
          wdf + ((size_t)((k * 4 + h) * 2 + 1)) * 512 + lane * 8);
      acc0 = __builtin_amdgcn_mfma_f32_32x32x16_bf16(afr, bf0, acc0, 0, 0, 0);
      acc1 = __builtin_amdgcn_mfma_f32_32x32x16_bf16(afr, bf1, acc1, 0, 0, 0);
    }
  }

  #pragma unroll
  for (int nt = 0; nt < 2; ++nt) {
    const int oc = nt * 32 + l31;
    const float inv = g[oc] * rsqrtf(v[oc] + EPSBN);
    const float sh = bb[oc] - m[oc] * inv;
    const f32x16& a = nt ? acc1 : acc0;
    #pragma unroll
    for (int r = 0; r < 16; ++r) {
      const int p = wv * 32 + (r & 3) + 8 * (r >> 2) + 4 * l5;
      const int y = y0 + (p >> 4), x = x0 + (p & 15);
      const float val = fmaxf(fmaf(a[r], inv, sh), 0.f);
      x2b[(((size_t)((b * 96 + y) * 96 + x)) << 6) + oc] = f2bf(val);
    }
  }
}

extern "C" void kernel_launch(void* const* d_in, const int* in_sizes, int n_in,
                              void* d_out, int out_size, void* d_ws,
                              size_t ws_size, hipStream_t stream)
{
  (void)in_sizes; (void)n_in; (void)out_size; (void)ws_size;
  const float* features = (const float*)d_in[0];
  const float* coord_w  = (const float*)d_in[1];
  const float* coord_b  = (const float*)d_in[2];
  const float* bn1g = (const float*)d_in[3];
  const float* bn1b = (const float*)d_in[4];
  const float* bn1m = (const float*)d_in[5];
  const float* bn1v = (const float*)d_in[6];
  const float* off_w = (const float*)d_in[7];
  const float* off_b = (const float*)d_in[8];
  const float* dc_w  = (const float*)d_in[9];
  const float* bn2g = (const float*)d_in[10];
  const float* bn2b = (const float*)d_in[11];
  const float* bn2m = (const float*)d_in[12];
  const float* bn2v = (const float*)d_in[13];
  const float* r1_w = (const float*)d_in[14];
  const float* bn3g = (const float*)d_in[15];
  const float* bn3b = (const float*)d_in[16];
  const float* bn3m = (const float*)d_in[17];
  const float* bn3v = (const float*)d_in[18];
  const float* r2_w = (const float*)d_in[19];
  const float* bn4g = (const float*)d_in[20];
  const float* bn4b = (const float*)d_in[21];
  const float* bn4m = (const float*)d_in[22];
  const float* bn4v = (const float*)d_in[23];
  const float* out_w = (const float*)d_in[24];
  const float* out_b = (const float*)d_in[25];

  char* W = (char*)d_ws;
  u16*   x1b = (u16*)(W + O_X1);
  u16*   x0b = (u16*)(W + O_X0B);
  u16*   x2b = (u16*)(W + O_X2);    // alias: x0b dead after coord conv
  u16*   x3b = (u16*)(W + O_X3);    // alias: x0b dead after coord conv
  float* offb = (float*)(W + O_OFF);
  float* pre = (float*)(W + O_PRE);
  u16*   wcf = (u16*)(W + O_WCF);
  u16*   wof = (u16*)(W + O_WOF);
  u16*   wdf = (u16*)(W + O_WDF);
  u16*   wr1 = (u16*)(W + O_WR1);
  u16*   wr2 = (u16*)(W + O_WR2);

  prep_kernel<<<2048, 256, 0, stream>>>(
      features, coord_w, coord_b, off_w, dc_w, r1_w, r2_w, x0b,
      wcf, wof, wdf, wr1, wr2, pre);

  dim3 grid(3, 24, 8);   // 32x4 tiles
  dim3 gridD(6, 12, 8);  // 16x8 tiles (deform)

  coord_conv_kernel<<<grid, 512, 0, stream>>>(
      x0b, wcf, pre, bn1g, bn1b, bn1m, bn1v, x1b);
  conv64_kernel<1><<<grid, 512, 0, stream>>>(
      x1b, wof, nullptr, nullptr, nullptr, nullptr, off_b, nullptr,
      (void*)offb);
  deform_kernel<<<gridD, 256, 0, stream>>>(
      x1b, offb, wdf, bn2g, bn2b, bn2m, bn2v, x2b);
  conv64_kernel<0><<<grid, 512, 0, stream>>>(
      x2b, wr1, bn3g, bn3b, bn3m, bn3v, nullptr, nullptr, (void*)x3b);
  conv64_kernel<2><<<grid, 512, 0, stream>>>(
      x3b, wr2, bn4g, bn4b, bn4m, bn4v, out_w, out_b, d_out);
}